// Round 6
// baseline (217.331 us; speedup 1.0000x reference)
//
#include <hip/hip_runtime.h>
#include <hip/hip_bf16.h>
#include <math.h>

#define B_ 2
#define C_ 64
#define H_ 192
#define W_ 192
#define HW_ (H_*W_)
#define BHW_ (B_*HW_)
#define KK_ 9
#define CK_ (C_*KK_)      // 576
#define KSTEPS_ (CK_/32)  // 18

typedef __bf16 bf16x8 __attribute__((ext_vector_type(8)));
typedef float  f32x4  __attribute__((ext_vector_type(4)));

__device__ __forceinline__ float bf2f(unsigned short u) {
    unsigned int t = ((unsigned int)u) << 16;
    return __builtin_bit_cast(float, t);
}

// ---------------- LayerNorm over channel axis -> bf16 ----------------------
__global__ void ln_kernel(const float* __restrict__ x,
                          const float* __restrict__ lnw,
                          const float* __restrict__ lnb,
                          unsigned short* __restrict__ xnb) {
    int p = blockIdx.x * blockDim.x + threadIdx.x;
    if (p >= BHW_) return;
    int b = p / HW_, pix = p % HW_;
    const float* xb = x + (size_t)b * C_ * HW_ + pix;
    float v[C_];
    float s = 0.f, s2 = 0.f;
    #pragma unroll
    for (int c = 0; c < C_; ++c) {
        v[c] = xb[(size_t)c * HW_];
        s += v[c]; s2 += v[c] * v[c];
    }
    float mu  = s * (1.0f / C_);
    float var = s2 * (1.0f / C_) - mu * mu;
    float inv = rsqrtf(var + 1e-5f);
    unsigned short* zb = xnb + (size_t)b * C_ * HW_ + pix;
    #pragma unroll
    for (int c = 0; c < C_; ++c) {
        float y = (v[c] - mu) * inv * lnw[c] + lnb[c];
        __hip_bfloat16 hb = __float2bfloat16(y);
        zb[(size_t)c * HW_] = *reinterpret_cast<unsigned short*>(&hb);
    }
}

// ---------------- weight prepack (all three GEMMs, tap-outer ck = k*64+c) ---
// wpack (deform 64oc), wpf (fusion 64oc), wpc (conv27 32oc: 18 off, 9 mask, 5 zero)
__global__ void prepack_kernel(const float* __restrict__ dw,
                               const float* __restrict__ fw,
                               const float* __restrict__ offw,
                               const float* __restrict__ maskw,
                               unsigned short* __restrict__ wpack,
                               unsigned short* __restrict__ wpf,
                               unsigned short* __restrict__ wpc) {
    const int n1 = 4 * KSTEPS_ * 64 * 8;   // 36864 (deform)
    const int n2 = 4 * KSTEPS_ * 64 * 8;   // 36864 (fusion)
    const int n3 = 2 * KSTEPS_ * 64 * 8;   // 18432 (conv27)
    int gid = blockIdx.x * blockDim.x + threadIdx.x;
    int nth = gridDim.x * blockDim.x;
    for (int idx = gid; idx < n1 + n2 + n3; idx += nth) {
        int which = (idx < n1) ? 0 : (idx < n1 + n2 ? 1 : 2);
        int rem = idx - (which == 0 ? 0 : (which == 1 ? n1 : n1 + n2));
        int j = rem & 7;
        int l = (rem >> 3) & 63;
        int rest = rem >> 9;
        int s = rest % KSTEPS_;
        int t = rest / KSTEPS_;
        int oc = t * 16 + (l & 15);
        int ck = s * 32 + (l >> 4) * 8 + j;
        int k = ck >> 6, c = ck & 63;        // tap-outer for all three
        float v;
        if (which == 0) {
            v = dw[(size_t)oc * CK_ + c * 9 + k];
        } else if (which == 1) {
            v = fw[(size_t)oc * CK_ + c * 9 + k];
        } else {
            v = (oc < 18) ? offw[(size_t)oc * CK_ + c * 9 + k]
              : (oc < 27) ? maskw[(size_t)(oc - 18) * CK_ + c * 9 + k]
              : 0.f;
        }
        __hip_bfloat16 hb = __float2bfloat16(v);
        unsigned short u = *reinterpret_cast<unsigned short*>(&hb);
        if (which == 0) wpack[rem] = u;
        else if (which == 1) wpf[rem] = u;
        else wpc[rem] = u;
    }
}

// ---------------- conv27 via MFMA: offset(18) + mask(9) --------------------
__global__ void __launch_bounds__(256) conv27_mfma(
        const unsigned short* __restrict__ xnb,
        const unsigned short* __restrict__ wpc,
        const float* __restrict__ offb, const float* __restrict__ maskb,
        float* __restrict__ offset, float* __restrict__ mask) {
    int wave = threadIdx.x >> 6;
    int lane = threadIdx.x & 63;
    int ptile = blockIdx.x * 4 + wave;
    int p = ptile * 16 + (lane & 15);
    int kchunk = lane >> 4;
    int b = p / HW_, pix = p - b * HW_;
    int h = pix / W_, w = pix - h * W_;

    f32x4 acc[2];
    #pragma unroll
    for (int t = 0; t < 2; ++t) acc[t] = f32x4{0.f, 0.f, 0.f, 0.f};

    const unsigned short* xb = xnb + (size_t)b * C_ * HW_;
    #pragma unroll
    for (int s = 0; s < KSTEPS_; ++s) {
        const int k = s >> 1;
        const int dy = k / 3 - 1, dx = k % 3 - 1;
        bool ok = ((unsigned)(h + dy) < (unsigned)H_) &&
                  ((unsigned)(w + dx) < (unsigned)W_);
        int sp = ok ? (pix + dy * W_ + dx) : pix;
        int cbase = (s & 1) * 32 + kchunk * 8;
        const unsigned short* vs = xb + (size_t)cbase * HW_ + sp;
        union { unsigned short u[8]; bf16x8 v; } bu;
        #pragma unroll
        for (int j = 0; j < 8; ++j)
            bu.u[j] = ok ? vs[(size_t)j * HW_] : (unsigned short)0;
        #pragma unroll
        for (int t = 0; t < 2; ++t) {
            bf16x8 afrag = *reinterpret_cast<const bf16x8*>(
                wpc + ((size_t)(t * KSTEPS_ + s) * 64 + lane) * 8);
            acc[t] = __builtin_amdgcn_mfma_f32_16x16x32_bf16(afrag, bu.v, acc[t], 0, 0, 0);
        }
    }

    #pragma unroll
    for (int t = 0; t < 2; ++t) {
        #pragma unroll
        for (int r = 0; r < 4; ++r) {
            int oc = t * 16 + kchunk * 4 + r;
            if (oc < 18) {
                offset[((size_t)b * 18 + oc) * HW_ + pix] = acc[t][r] + offb[oc];
            } else if (oc < 27) {
                float a = acc[t][r] + maskb[oc - 18];
                mask[((size_t)b * 9 + (oc - 18)) * HW_ + pix] = 1.f / (1.f + expf(-a));
            }
        }
    }
}

// ---------------- fused deform: bilinear gather + MFMA contraction ---------
// wave = 16 pixels x 64 oc; K-order tap-outer: step s -> tap k=s>>1 fixed.
// Lane builds B-fragment by gathering 8 channels x 4 corners from xnb.
__global__ void __launch_bounds__(256) deform_mfma(
        const unsigned short* __restrict__ xnb,
        const float* __restrict__ offset,
        const float* __restrict__ mask,
        const unsigned short* __restrict__ wpack,
        const float* __restrict__ db,
        unsigned short* __restrict__ xdefb) {
    int wave = threadIdx.x >> 6;
    int lane = threadIdx.x & 63;
    int ptile = blockIdx.x * 4 + wave;
    int p = ptile * 16 + (lane & 15);
    int kchunk = lane >> 4;
    int b = p / HW_, pix = p - b * HW_;
    int h = pix / W_, w = pix - h * W_;

    f32x4 acc[4];
    #pragma unroll
    for (int t = 0; t < 4; ++t) acc[t] = f32x4{0.f, 0.f, 0.f, 0.f};

    const unsigned short* xb = xnb + (size_t)b * C_ * HW_;

    #pragma unroll
    for (int k = 0; k < KK_; ++k) {
        // per-tap bilinear setup (per lane's own pixel)
        float dy = offset[((size_t)b * 18 + 2 * k) * HW_ + pix];
        float dx = offset[((size_t)b * 18 + 2 * k + 1) * HW_ + pix];
        float m  = mask[((size_t)b * 9 + k) * HW_ + pix];
        float py = dy + (float)(h - 1 + k / 3);
        float px = dx + (float)(w - 1 + k % 3);
        float fy = floorf(py), fx = floorf(px);
        float ly = py - fy, lx = px - fx;
        int y0 = (int)fy, x0 = (int)fx;
        int y1 = y0 + 1, x1 = x0 + 1;
        bool oky0 = (unsigned)y0 < (unsigned)H_;
        bool oky1 = (unsigned)y1 < (unsigned)H_;
        bool okx0 = (unsigned)x0 < (unsigned)W_;
        bool okx1 = (unsigned)x1 < (unsigned)W_;
        int cy0 = min(max(y0, 0), H_ - 1), cy1 = min(max(y1, 0), H_ - 1);
        int cx0 = min(max(x0, 0), W_ - 1), cx1 = min(max(x1, 0), W_ - 1);
        int a00 = cy0 * W_ + cx0, a01 = cy0 * W_ + cx1;
        int a10 = cy1 * W_ + cx0, a11 = cy1 * W_ + cx1;
        float q00 = (oky0 && okx0) ? (1.f - ly) * (1.f - lx) * m : 0.f;
        float q01 = (oky0 && okx1) ? (1.f - ly) * lx * m : 0.f;
        float q10 = (oky1 && okx0) ? ly * (1.f - lx) * m : 0.f;
        float q11 = (oky1 && okx1) ? ly * lx * m : 0.f;

        #pragma unroll
        for (int half = 0; half < 2; ++half) {
            int s = k * 2 + half;
            int cbase = half * 32 + kchunk * 8;
            const unsigned short* xc = xb + (size_t)cbase * HW_;
            union { unsigned short u[8]; bf16x8 v; } bu;
            #pragma unroll
            for (int j = 0; j < 8; ++j) {
                const unsigned short* xj = xc + (size_t)j * HW_;
                float v = q00 * bf2f(xj[a00]) + q01 * bf2f(xj[a01])
                        + q10 * bf2f(xj[a10]) + q11 * bf2f(xj[a11]);
                __hip_bfloat16 hb = __float2bfloat16(v);
                bu.u[j] = *reinterpret_cast<unsigned short*>(&hb);
            }
            #pragma unroll
            for (int t = 0; t < 4; ++t) {
                bf16x8 afrag = *reinterpret_cast<const bf16x8*>(
                    wpack + ((size_t)(t * KSTEPS_ + s) * 64 + lane) * 8);
                acc[t] = __builtin_amdgcn_mfma_f32_16x16x32_bf16(afrag, bu.v, acc[t], 0, 0, 0);
            }
        }
    }

    #pragma unroll
    for (int t = 0; t < 4; ++t) {
        #pragma unroll
        for (int r = 0; r < 4; ++r) {
            int oc = t * 16 + kchunk * 4 + r;
            __hip_bfloat16 hb = __float2bfloat16(acc[t][r] + db[oc]);
            xdefb[((size_t)b * C_ + oc) * HW_ + pix] =
                *reinterpret_cast<unsigned short*>(&hb);
        }
    }
}

// ---------------- fusion conv via MFMA + pre_mask blend --------------------
__global__ void __launch_bounds__(256) fuse_mfma(
        const unsigned short* __restrict__ xdefb,
        const unsigned short* __restrict__ wpf,
        const float* __restrict__ fb,
        const float* __restrict__ premask,
        const float* __restrict__ xin,
        float* __restrict__ out) {
    int wave = threadIdx.x >> 6;
    int lane = threadIdx.x & 63;
    int ptile = blockIdx.x * 4 + wave;
    int p = ptile * 16 + (lane & 15);
    int kchunk = lane >> 4;
    int b = p / HW_, pix = p - b * HW_;
    int h = pix / W_, w = pix - h * W_;

    f32x4 acc[4];
    #pragma unroll
    for (int t = 0; t < 4; ++t) acc[t] = f32x4{0.f, 0.f, 0.f, 0.f};

    const unsigned short* xb = xdefb + (size_t)b * C_ * HW_;
    #pragma unroll
    for (int s = 0; s < KSTEPS_; ++s) {
        const int k = s >> 1;
        const int dy = k / 3 - 1, dx = k % 3 - 1;
        bool ok = ((unsigned)(h + dy) < (unsigned)H_) &&
                  ((unsigned)(w + dx) < (unsigned)W_);
        int sp = ok ? (pix + dy * W_ + dx) : pix;
        int cbase = (s & 1) * 32 + kchunk * 8;
        const unsigned short* vs = xb + (size_t)cbase * HW_ + sp;
        union { unsigned short u[8]; bf16x8 v; } bu;
        #pragma unroll
        for (int j = 0; j < 8; ++j)
            bu.u[j] = ok ? vs[(size_t)j * HW_] : (unsigned short)0;
        #pragma unroll
        for (int t = 0; t < 4; ++t) {
            bf16x8 afrag = *reinterpret_cast<const bf16x8*>(
                wpf + ((size_t)(t * KSTEPS_ + s) * 64 + lane) * 8);
            acc[t] = __builtin_amdgcn_mfma_f32_16x16x32_bf16(afrag, bu.v, acc[t], 0, 0, 0);
        }
    }

    float pm = premask[(size_t)b * HW_ + pix];
    #pragma unroll
    for (int t = 0; t < 4; ++t) {
        #pragma unroll
        for (int r = 0; r < 4; ++r) {
            int oc = t * 16 + kchunk * 4 + r;
            size_t oidx = ((size_t)b * C_ + oc) * HW_ + pix;
            out[oidx] = (acc[t][r] + fb[oc]) * pm + xin[oidx] * (1.f - pm);
        }
    }
}

extern "C" void kernel_launch(void* const* d_in, const int* in_sizes, int n_in,
                              void* d_out, int out_size, void* d_ws, size_t ws_size,
                              hipStream_t stream) {
    const float* x       = (const float*)d_in[0];
    const float* premask = (const float*)d_in[1];
    const float* lnw     = (const float*)d_in[2];
    const float* lnb     = (const float*)d_in[3];
    const float* offw    = (const float*)d_in[4];
    const float* offb    = (const float*)d_in[5];
    const float* maskw   = (const float*)d_in[6];
    const float* maskb   = (const float*)d_in[7];
    const float* dw      = (const float*)d_in[8];
    const float* db      = (const float*)d_in[9];
    const float* fw      = (const float*)d_in[10];
    const float* fb      = (const float*)d_in[11];
    float* out = (float*)d_out;

    char* ws = (char*)d_ws;
    unsigned short* xnb   = (unsigned short*)ws;  ws += sizeof(short) * B_ * C_ * HW_;
    float* offset         = (float*)ws;           ws += sizeof(float) * B_ * 18 * HW_;
    float* mask           = (float*)ws;           ws += sizeof(float) * B_ * 9 * HW_;
    unsigned short* xdefb = (unsigned short*)ws;  ws += sizeof(short) * B_ * C_ * HW_;
    unsigned short* wpack = (unsigned short*)ws;  ws += sizeof(short) * 4 * KSTEPS_ * 64 * 8;
    unsigned short* wpf   = (unsigned short*)ws;  ws += sizeof(short) * 4 * KSTEPS_ * 64 * 8;
    unsigned short* wpc   = (unsigned short*)ws;  ws += sizeof(short) * 2 * KSTEPS_ * 64 * 8;

    ln_kernel<<<(BHW_ + 255) / 256, 256, 0, stream>>>(x, lnw, lnb, xnb);
    prepack_kernel<<<36, 256, 0, stream>>>(dw, fw, offw, maskw, wpack, wpf, wpc);
    conv27_mfma<<<BHW_ / 64, 256, 0, stream>>>(xnb, wpc, offb, maskb, offset, mask);
    deform_mfma<<<BHW_ / 64, 256, 0, stream>>>(
        xnb, offset, mask, wpack, db, xdefb);
    fuse_mfma<<<BHW_ / 64, 256, 0, stream>>>(
        xdefb, wpf, fb, premask, x, out);
}

// Round 7
// 125.809 us; speedup vs baseline: 1.7275x; 1.7275x over previous
//
#include <hip/hip_runtime.h>
#include <hip/hip_bf16.h>
#include <math.h>

#define B_ 2
#define C_ 64
#define H_ 192
#define W_ 192
#define HW_ (H_*W_)
#define BHW_ (B_*HW_)
#define KK_ 9
#define CK_ (C_*KK_)      // 576
#define KSTEPS_ (CK_/32)  // 18

typedef __bf16 bf16x8 __attribute__((ext_vector_type(8)));
typedef float  f32x4  __attribute__((ext_vector_type(4)));
typedef unsigned short ushortx8 __attribute__((ext_vector_type(8)));
typedef unsigned short ushortx4 __attribute__((ext_vector_type(4)));

__device__ __forceinline__ float bf2f(unsigned short u) {
    unsigned int t = ((unsigned int)u) << 16;
    return __builtin_bit_cast(float, t);
}
__device__ __forceinline__ unsigned short f2bf(float f) {
    __hip_bfloat16 hb = __float2bfloat16(f);
    return *reinterpret_cast<unsigned short*>(&hb);
}

// ---------------- LayerNorm over channel axis -> bf16 NHWC ------------------
__global__ void ln_kernel(const float* __restrict__ x,
                          const float* __restrict__ lnw,
                          const float* __restrict__ lnb,
                          unsigned short* __restrict__ xnb) {   // [BHW][64]
    int p = blockIdx.x * blockDim.x + threadIdx.x;
    if (p >= BHW_) return;
    int b = p / HW_, pix = p % HW_;
    const float* xb = x + (size_t)b * C_ * HW_ + pix;
    float v[C_];
    float s = 0.f, s2 = 0.f;
    #pragma unroll
    for (int c = 0; c < C_; ++c) {
        v[c] = xb[(size_t)c * HW_];
        s += v[c]; s2 += v[c] * v[c];
    }
    float mu  = s * (1.0f / C_);
    float var = s2 * (1.0f / C_) - mu * mu;
    float inv = rsqrtf(var + 1e-5f);
    unsigned short* zb = xnb + (size_t)p * 64;
    #pragma unroll
    for (int g = 0; g < 8; ++g) {
        ushortx8 st;
        #pragma unroll
        for (int j = 0; j < 8; ++j) {
            int c = g * 8 + j;
            st[j] = f2bf((v[c] - mu) * inv * lnw[c] + lnb[c]);
        }
        *reinterpret_cast<ushortx8*>(zb + g * 8) = st;
    }
}

// ---------------- weight prepack (tap-outer ck = k*64+c) -------------------
__global__ void prepack_kernel(const float* __restrict__ dw,
                               const float* __restrict__ fw,
                               const float* __restrict__ offw,
                               const float* __restrict__ maskw,
                               unsigned short* __restrict__ wpack,
                               unsigned short* __restrict__ wpf,
                               unsigned short* __restrict__ wpc) {
    const int n1 = 4 * KSTEPS_ * 64 * 8;   // deform
    const int n2 = 4 * KSTEPS_ * 64 * 8;   // fusion
    const int n3 = 2 * KSTEPS_ * 64 * 8;   // conv27
    int gid = blockIdx.x * blockDim.x + threadIdx.x;
    int nth = gridDim.x * blockDim.x;
    for (int idx = gid; idx < n1 + n2 + n3; idx += nth) {
        int which = (idx < n1) ? 0 : (idx < n1 + n2 ? 1 : 2);
        int rem = idx - (which == 0 ? 0 : (which == 1 ? n1 : n1 + n2));
        int j = rem & 7;
        int l = (rem >> 3) & 63;
        int rest = rem >> 9;
        int s = rest % KSTEPS_;
        int t = rest / KSTEPS_;
        int oc = t * 16 + (l & 15);
        int ck = s * 32 + (l >> 4) * 8 + j;
        int k = ck >> 6, c = ck & 63;
        float v;
        if (which == 0) {
            v = dw[(size_t)oc * CK_ + c * 9 + k];
        } else if (which == 1) {
            v = fw[(size_t)oc * CK_ + c * 9 + k];
        } else {
            v = (oc < 18) ? offw[(size_t)oc * CK_ + c * 9 + k]
              : (oc < 27) ? maskw[(size_t)(oc - 18) * CK_ + c * 9 + k]
              : 0.f;
        }
        unsigned short u = f2bf(v);
        if (which == 0) wpack[rem] = u;
        else if (which == 1) wpf[rem] = u;
        else wpc[rem] = u;
    }
}

// ---------------- conv27 via MFMA -> opix[BHW][32] -------------------------
// rows 0..17: offset (+bias); 18..26: sigmoid(mask conv + bias); 27..31 pad
__global__ void __launch_bounds__(256) conv27_mfma(
        const unsigned short* __restrict__ xnb,   // NHWC
        const unsigned short* __restrict__ wpc,
        const float* __restrict__ offb, const float* __restrict__ maskb,
        float* __restrict__ opix) {
    int wave = threadIdx.x >> 6;
    int lane = threadIdx.x & 63;
    int ptile = blockIdx.x * 4 + wave;
    int p = ptile * 16 + (lane & 15);
    int kchunk = lane >> 4;
    int b = p / HW_, pix = p - b * HW_;
    int h = pix / W_, w = pix - h * W_;

    f32x4 acc[2];
    #pragma unroll
    for (int t = 0; t < 2; ++t) acc[t] = f32x4{0.f, 0.f, 0.f, 0.f};

    const unsigned short* xb = xnb + (size_t)b * HW_ * 64;
    #pragma unroll
    for (int s = 0; s < KSTEPS_; ++s) {
        const int k = s >> 1;
        const int dy = k / 3 - 1, dx = k % 3 - 1;
        bool ok = ((unsigned)(h + dy) < (unsigned)H_) &&
                  ((unsigned)(w + dx) < (unsigned)W_);
        int sp = ok ? (pix + dy * W_ + dx) : pix;
        int cbase = (s & 1) * 32 + kchunk * 8;
        union { ushortx8 u; bf16x8 v; } bu;
        bu.u = ok ? *reinterpret_cast<const ushortx8*>(xb + (size_t)sp * 64 + cbase)
                  : ushortx8{0,0,0,0,0,0,0,0};
        #pragma unroll
        for (int t = 0; t < 2; ++t) {
            bf16x8 afrag = *reinterpret_cast<const bf16x8*>(
                wpc + ((size_t)(t * KSTEPS_ + s) * 64 + lane) * 8);
            acc[t] = __builtin_amdgcn_mfma_f32_16x16x32_bf16(afrag, bu.v, acc[t], 0, 0, 0);
        }
    }

    float* orow = opix + (size_t)p * 32;
    #pragma unroll
    for (int t = 0; t < 2; ++t) {
        f32x4 sv;
        #pragma unroll
        for (int r = 0; r < 4; ++r) {
            int oc = t * 16 + kchunk * 4 + r;
            float a = acc[t][r];
            if (oc < 18)       sv[r] = a + offb[oc];
            else if (oc < 27)  sv[r] = 1.f / (1.f + expf(-(a + maskb[oc - 18])));
            else               sv[r] = 0.f;
        }
        *reinterpret_cast<f32x4*>(orow + t * 16 + kchunk * 4) = sv;
    }
}

// ---------------- fused deform: bilinear gather + MFMA ---------------------
// NHWC: each corner's 8-channel group is ONE 16B load.
__global__ void __launch_bounds__(256) deform_mfma(
        const unsigned short* __restrict__ xnb,   // NHWC
        const float* __restrict__ opix,           // [BHW][32]
        const unsigned short* __restrict__ wpack,
        const float* __restrict__ db,
        unsigned short* __restrict__ xdefb) {     // NHWC
    int wave = threadIdx.x >> 6;
    int lane = threadIdx.x & 63;
    int ptile = blockIdx.x * 4 + wave;
    int p = ptile * 16 + (lane & 15);
    int kchunk = lane >> 4;
    int b = p / HW_, pix = p - b * HW_;
    int h = pix / W_, w = pix - h * W_;

    // offset/mask row: 7 x f32x4
    float om[28];
    const f32x4* orow = reinterpret_cast<const f32x4*>(opix + (size_t)p * 32);
    #pragma unroll
    for (int i = 0; i < 7; ++i) {
        f32x4 t4 = orow[i];
        om[4 * i + 0] = t4[0]; om[4 * i + 1] = t4[1];
        om[4 * i + 2] = t4[2]; om[4 * i + 3] = t4[3];
    }

    f32x4 acc[4];
    #pragma unroll
    for (int t = 0; t < 4; ++t) acc[t] = f32x4{0.f, 0.f, 0.f, 0.f};

    const unsigned short* xb = xnb + (size_t)b * HW_ * 64;

    #pragma unroll
    for (int k = 0; k < KK_; ++k) {
        float dy = om[2 * k], dx = om[2 * k + 1], m = om[18 + k];
        float py = dy + (float)(h - 1 + k / 3);
        float px = dx + (float)(w - 1 + k % 3);
        float fy = floorf(py), fx = floorf(px);
        float ly = py - fy, lx = px - fx;
        int y0 = (int)fy, x0 = (int)fx;
        int y1 = y0 + 1, x1 = x0 + 1;
        bool oky0 = (unsigned)y0 < (unsigned)H_;
        bool oky1 = (unsigned)y1 < (unsigned)H_;
        bool okx0 = (unsigned)x0 < (unsigned)W_;
        bool okx1 = (unsigned)x1 < (unsigned)W_;
        int cy0 = min(max(y0, 0), H_ - 1), cy1 = min(max(y1, 0), H_ - 1);
        int cx0 = min(max(x0, 0), W_ - 1), cx1 = min(max(x1, 0), W_ - 1);
        int a00 = cy0 * W_ + cx0, a01 = cy0 * W_ + cx1;
        int a10 = cy1 * W_ + cx0, a11 = cy1 * W_ + cx1;
        float q00 = (oky0 && okx0) ? (1.f - ly) * (1.f - lx) * m : 0.f;
        float q01 = (oky0 && okx1) ? (1.f - ly) * lx * m : 0.f;
        float q10 = (oky1 && okx0) ? ly * (1.f - lx) * m : 0.f;
        float q11 = (oky1 && okx1) ? ly * lx * m : 0.f;

        #pragma unroll
        for (int half = 0; half < 2; ++half) {
            int s = k * 2 + half;
            int cbase = half * 32 + kchunk * 8;
            ushortx8 c00 = *reinterpret_cast<const ushortx8*>(xb + (size_t)a00 * 64 + cbase);
            ushortx8 c01 = *reinterpret_cast<const ushortx8*>(xb + (size_t)a01 * 64 + cbase);
            ushortx8 c10 = *reinterpret_cast<const ushortx8*>(xb + (size_t)a10 * 64 + cbase);
            ushortx8 c11 = *reinterpret_cast<const ushortx8*>(xb + (size_t)a11 * 64 + cbase);
            union { unsigned short u[8]; bf16x8 v; } bu;
            #pragma unroll
            for (int j = 0; j < 8; ++j) {
                float v = q00 * bf2f(c00[j]) + q01 * bf2f(c01[j])
                        + q10 * bf2f(c10[j]) + q11 * bf2f(c11[j]);
                bu.u[j] = f2bf(v);
            }
            #pragma unroll
            for (int t = 0; t < 4; ++t) {
                bf16x8 afrag = *reinterpret_cast<const bf16x8*>(
                    wpack + ((size_t)(t * KSTEPS_ + s) * 64 + lane) * 8);
                acc[t] = __builtin_amdgcn_mfma_f32_16x16x32_bf16(afrag, bu.v, acc[t], 0, 0, 0);
            }
        }
    }

    unsigned short* zb = xdefb + (size_t)p * 64;
    #pragma unroll
    for (int t = 0; t < 4; ++t) {
        ushortx4 st;
        #pragma unroll
        for (int r = 0; r < 4; ++r) {
            int oc = t * 16 + kchunk * 4 + r;
            st[r] = f2bf(acc[t][r] + db[oc]);
        }
        *reinterpret_cast<ushortx4*>(zb + t * 16 + kchunk * 4) = st;
    }
}

// ---------------- fusion conv via MFMA + pre_mask blend --------------------
__global__ void __launch_bounds__(256) fuse_mfma(
        const unsigned short* __restrict__ xdefb,  // NHWC
        const unsigned short* __restrict__ wpf,
        const float* __restrict__ fb,
        const float* __restrict__ premask,
        const float* __restrict__ xin,             // NCHW
        float* __restrict__ out) {                 // NCHW
    int wave = threadIdx.x >> 6;
    int lane = threadIdx.x & 63;
    int ptile = blockIdx.x * 4 + wave;
    int p = ptile * 16 + (lane & 15);
    int kchunk = lane >> 4;
    int b = p / HW_, pix = p - b * HW_;
    int h = pix / W_, w = pix - h * W_;

    f32x4 acc[4];
    #pragma unroll
    for (int t = 0; t < 4; ++t) acc[t] = f32x4{0.f, 0.f, 0.f, 0.f};

    const unsigned short* xb = xdefb + (size_t)b * HW_ * 64;
    #pragma unroll
    for (int s = 0; s < KSTEPS_; ++s) {
        const int k = s >> 1;
        const int dy = k / 3 - 1, dx = k % 3 - 1;
        bool ok = ((unsigned)(h + dy) < (unsigned)H_) &&
                  ((unsigned)(w + dx) < (unsigned)W_);
        int sp = ok ? (pix + dy * W_ + dx) : pix;
        int cbase = (s & 1) * 32 + kchunk * 8;
        union { ushortx8 u; bf16x8 v; } bu;
        bu.u = ok ? *reinterpret_cast<const ushortx8*>(xb + (size_t)sp * 64 + cbase)
                  : ushortx8{0,0,0,0,0,0,0,0};
        #pragma unroll
        for (int t = 0; t < 4; ++t) {
            bf16x8 afrag = *reinterpret_cast<const bf16x8*>(
                wpf + ((size_t)(t * KSTEPS_ + s) * 64 + lane) * 8);
            acc[t] = __builtin_amdgcn_mfma_f32_16x16x32_bf16(afrag, bu.v, acc[t], 0, 0, 0);
        }
    }

    float pm = premask[(size_t)b * HW_ + pix];
    #pragma unroll
    for (int t = 0; t < 4; ++t) {
        #pragma unroll
        for (int r = 0; r < 4; ++r) {
            int oc = t * 16 + kchunk * 4 + r;
            size_t oidx = ((size_t)b * C_ + oc) * HW_ + pix;
            out[oidx] = (acc[t][r] + fb[oc]) * pm + xin[oidx] * (1.f - pm);
        }
    }
}

extern "C" void kernel_launch(void* const* d_in, const int* in_sizes, int n_in,
                              void* d_out, int out_size, void* d_ws, size_t ws_size,
                              hipStream_t stream) {
    const float* x       = (const float*)d_in[0];
    const float* premask = (const float*)d_in[1];
    const float* lnw     = (const float*)d_in[2];
    const float* lnb     = (const float*)d_in[3];
    const float* offw    = (const float*)d_in[4];
    const float* offb    = (const float*)d_in[5];
    const float* maskw   = (const float*)d_in[6];
    const float* maskb   = (const float*)d_in[7];
    const float* dw      = (const float*)d_in[8];
    const float* db      = (const float*)d_in[9];
    const float* fw      = (const float*)d_in[10];
    const float* fb      = (const float*)d_in[11];
    float* out = (float*)d_out;

    char* ws = (char*)d_ws;
    unsigned short* xnb   = (unsigned short*)ws;  ws += sizeof(short) * (size_t)BHW_ * 64;
    float* opix           = (float*)ws;           ws += sizeof(float) * (size_t)BHW_ * 32;
    unsigned short* xdefb = (unsigned short*)ws;  ws += sizeof(short) * (size_t)BHW_ * 64;
    unsigned short* wpack = (unsigned short*)ws;  ws += sizeof(short) * 4 * KSTEPS_ * 64 * 8;
    unsigned short* wpf   = (unsigned short*)ws;  ws += sizeof(short) * 4 * KSTEPS_ * 64 * 8;
    unsigned short* wpc   = (unsigned short*)ws;  ws += sizeof(short) * 2 * KSTEPS_ * 64 * 8;

    ln_kernel<<<(BHW_ + 255) / 256, 256, 0, stream>>>(x, lnw, lnb, xnb);
    prepack_kernel<<<36, 256, 0, stream>>>(dw, fw, offw, maskw, wpack, wpf, wpc);
    conv27_mfma<<<BHW_ / 64, 256, 0, stream>>>(xnb, wpc, offb, maskb, opix);
    deform_mfma<<<BHW_ / 64, 256, 0, stream>>>(xnb, opix, wpack, db, xdefb);
    fuse_mfma<<<BHW_ / 64, 256, 0, stream>>>(xdefb, wpf, fb, premask, x, out);
}